// Round 1
// baseline (242.820 us; speedup 1.0000x reference)
//
#include <hip/hip_runtime.h>

#define BATCH 256
#define CHAN  3
#define HIN   256
#define WIN   256
#define HOUT  64
#define WOUT  64

__global__ __launch_bounds__(256) void st_kernel(
    const float* __restrict__ x,
    const float* __restrict__ zw,
    const int*   __restrict__ inv_p,
    float*       __restrict__ out)
{
    const int tid = blockIdx.x * 256 + threadIdx.x;  // = b*4096 + oy*64 + ox
    const int ox = tid & 63;
    const int oy = (tid >> 6) & 63;
    const int b  = tid >> 12;

    // per-batch transform params (block-uniform: each block covers one b)
    const float z0 = zw[b * 4 + 0];
    const float z1 = zw[b * 4 + 1];
    const float z2 = zw[b * 4 + 2];
    const float z3 = zw[b * 4 + 3];

    float sx, sy, tx, ty;
    if (inv_p[0]) {
        const float s0 = z0 + 1e-6f, s1 = z1 + 1e-6f;
        sx = 1.0f / s0;  sy = 1.0f / s1;
        tx = -z2 / s0;   ty = -z3 / s1;
    } else {
        sx = z0; sy = z1; tx = z2; ty = z3;
    }

    // normalized output coords -> source pixel coords (match ref op order)
    const float xs = (2.0f * (float)ox + 1.0f) / (float)WOUT - 1.0f;
    const float ys = (2.0f * (float)oy + 1.0f) / (float)HOUT - 1.0f;
    const float u = sx * xs + tx;
    const float v = sy * ys + ty;
    const float ix = ((u + 1.0f) * (float)WIN - 1.0f) * 0.5f;
    const float iy = ((v + 1.0f) * (float)HIN - 1.0f) * 0.5f;

    const float fx0 = floorf(ix), fy0 = floorf(iy);
    const int x0 = (int)fx0, y0 = (int)fy0;
    const int x1 = x0 + 1,   y1 = y0 + 1;

    const float wx1 = ix - fx0, wx0 = 1.0f - wx1;
    const float wy1 = iy - fy0, wy0 = 1.0f - wy1;

    const bool vx0 = (x0 >= 0) && (x0 < WIN);
    const bool vx1 = (x1 >= 0) && (x1 < WIN);
    const bool vy0 = (y0 >= 0) && (y0 < HIN);
    const bool vy1 = (y1 >= 0) && (y1 < HIN);

    // zeros padding == zero the weight of any invalid corner
    float w00 = (vy0 && vx0) ? (wy0 * wx0) : 0.0f;
    float w01 = (vy0 && vx1) ? (wy0 * wx1) : 0.0f;
    float w10 = (vy1 && vx0) ? (wy1 * wx0) : 0.0f;
    float w11 = (vy1 && vx1) ? (wy1 * wx1) : 0.0f;

    const int xc0 = min(max(x0, 0), WIN - 1);
    const int xc1 = min(max(x1, 0), WIN - 1);
    const int yc0 = min(max(y0, 0), HIN - 1);
    const int yc1 = min(max(y1, 0), HIN - 1);

    const int o00 = yc0 * WIN + xc0;
    const int o01 = yc0 * WIN + xc1;
    const int o10 = yc1 * WIN + xc0;
    const int o11 = yc1 * WIN + xc1;

    const float* __restrict__ xb = x + (size_t)b * (CHAN * HIN * WIN);
    float* __restrict__ ob = out + (size_t)b * (CHAN * HOUT * WOUT) + oy * WOUT + ox;

#pragma unroll
    for (int c = 0; c < CHAN; ++c) {
        const float* __restrict__ xc = xb + c * (HIN * WIN);
        const float r = xc[o00] * w00 + xc[o01] * w01
                      + xc[o10] * w10 + xc[o11] * w11;
        ob[c * (HOUT * WOUT)] = r;
    }
}

extern "C" void kernel_launch(void* const* d_in, const int* in_sizes, int n_in,
                              void* d_out, int out_size, void* d_ws, size_t ws_size,
                              hipStream_t stream) {
    const float* x   = (const float*)d_in[0];
    const float* zw  = (const float*)d_in[1];
    const int*   inv = (const int*)d_in[2];
    float* out = (float*)d_out;

    const int total  = BATCH * HOUT * WOUT;   // one thread per (b, oy, ox)
    const int blocks = total / 256;           // 4096
    st_kernel<<<blocks, 256, 0, stream>>>(x, zw, inv, out);
}